// Round 2
// baseline (274.030 us; speedup 1.0000x reference)
//
#include <hip/hip_runtime.h>
#include <hip/hip_bf16.h>

typedef __bf16 bf16;
typedef __attribute__((ext_vector_type(8))) __bf16 bf16x8;
typedef __attribute__((ext_vector_type(4))) float f32x4;

#define T_SEQ 4096
#define D_EMB 1024
#define HS 64
#define NBATCH 4

// ---------------------------------------------------------------------------
// Kernel 0: cast Wk|Wv (fp32, 64x1024 each) -> bf16 workspace copies.
// 131072 elements, 8 per thread -> 16384 threads = 64 blocks x 256.
// ---------------------------------------------------------------------------
__global__ __launch_bounds__(256) void wcast_kernel(
    const float* __restrict__ Wk, const float* __restrict__ Wv,
    bf16* __restrict__ wbf)   // [2][64][1024]
{
    const int t = blockIdx.x * 256 + threadIdx.x;
    const int base = t * 8;                 // 0 .. 131064
    const float* src = (base < 65536) ? (Wk + base) : (Wv + base - 65536);
    float4 f0 = *(const float4*)(src);
    float4 f1 = *(const float4*)(src + 4);
    bf16x8 o = {(__bf16)f0.x, (__bf16)f0.y, (__bf16)f0.z, (__bf16)f0.w,
                (__bf16)f1.x, (__bf16)f1.y, (__bf16)f1.z, (__bf16)f1.w};
    *(bf16x8*)(wbf + base) = o;
}

// ---------------------------------------------------------------------------
// Kernel 1: fused projection GEMM (x fp32 -> bf16 fragments in-register).
//   k[t,h]  = sum_d x[t,d] * Wk[h,d]
//   qv[t,h] = sum_d x[t,d] * Wv[h,d]
// M = 16384 rows, N = 128 (64 k + 64 qv), K = 1024.
// Block = 4 waves; wave handles 16 rows x 128 cols; grid = 256.
// Also writes qvT [B][64][T] so attention PV B-fragments are contiguous.
// ---------------------------------------------------------------------------
__global__ __launch_bounds__(256) void proj_kernel(
    const float* __restrict__ x,    // [16384][1024] fp32
    const bf16* __restrict__ wbf,   // [128][1024] bf16 (Wk rows 0-63, Wv 64-127)
    bf16* __restrict__ kmat,        // [16384][64]
    bf16* __restrict__ qvmat,       // [16384][64]
    bf16* __restrict__ qvT)         // [4][64][4096]
{
    const int lane = threadIdx.x & 63;
    const int wave = threadIdx.x >> 6;
    const int col  = lane & 15;
    const int quad = lane >> 4;
    const int rowbase = blockIdx.x * 64 + wave * 16;

    // A-fragment row: m = lane&15
    const float* xrow = x + (size_t)(rowbase + col) * D_EMB;

    f32x4 acc[8];
#pragma unroll
    for (int i = 0; i < 8; ++i) acc[i] = {0.f, 0.f, 0.f, 0.f};

    for (int k0 = 0; k0 < D_EMB; k0 += 32) {
        float4 a0 = *(const float4*)(xrow + k0 + quad * 8);
        float4 a1 = *(const float4*)(xrow + k0 + quad * 8 + 4);
        bf16x8 a = {(__bf16)a0.x, (__bf16)a0.y, (__bf16)a0.z, (__bf16)a0.w,
                    (__bf16)a1.x, (__bf16)a1.y, (__bf16)a1.z, (__bf16)a1.w};
#pragma unroll
        for (int nt = 0; nt < 8; ++nt) {
            // B[k=d][n=h]: lane n=col -> W row nt*16+col; k = quad*8+j
            const bf16* wrow = wbf + (size_t)(nt * 16 + col) * D_EMB;
            bf16x8 b = *(const bf16x8*)(wrow + k0 + quad * 8);
            acc[nt] = __builtin_amdgcn_mfma_f32_16x16x32_bf16(a, b, acc[nt], 0, 0, 0);
        }
    }

    // Epilogue: C/D layout col=lane&15, row=quad*4+reg  (m89/m91 verified)
#pragma unroll
    for (int nt = 0; nt < 8; ++nt) {
        const int c = (nt & 3) * 16 + col;
#pragma unroll
        for (int r = 0; r < 4; ++r) {
            const int t = rowbase + quad * 4 + r;
            bf16 v = (bf16)acc[nt][r];
            if (nt < 4) {
                kmat[(size_t)t * HS + c] = v;
            } else {
                qvmat[(size_t)t * HS + c] = v;
                const int bb = t >> 12;            // t / 4096
                const int tt = t & (T_SEQ - 1);
                qvT[((size_t)bb * HS + c) * T_SEQ + tt] = v;
            }
        }
    }
}

// ---------------------------------------------------------------------------
// Kernel 2: causal flash attention with q = v = qv (bf16 in, fp32 out).
// One wave owns 16 query rows; iterates 32-wide K-tiles with online softmax.
// S = qv_q @ k_s^T * (1/8); P -> LDS roundtrip (C-layout -> A-layout, m120);
// O += P @ V using qvT for contiguous B-fragments.
// ---------------------------------------------------------------------------
__global__ __launch_bounds__(256) void attn_kernel(
    const bf16* __restrict__ kmat,   // [B*T][64]
    const bf16* __restrict__ qvmat,  // [B*T][64]
    const bf16* __restrict__ qvT,    // [B][64][T]
    float* __restrict__ out)         // [B*T][64] fp32
{
    // per-wave P buffer, rows padded to 40 bf16 (80 B = 20 banks; 2-way = free)
    __shared__ bf16 plds[4][16][40];

    const int lane = threadIdx.x & 63;
    const int wave = threadIdx.x >> 6;
    const int col  = lane & 15;
    const int quad = lane >> 4;

    const int gw = blockIdx.x * 4 + wave;   // 0..1023
    const int b  = gw >> 8;                 // batch
    const int g  = gw & 255;                // q-group within batch
    const int q0 = g * 16;

    const bf16* qvb = qvmat + (size_t)b * T_SEQ * HS;
    const bf16* kb  = kmat  + (size_t)b * T_SEQ * HS;
    const bf16* vTb = qvT   + (size_t)b * HS * T_SEQ;

    // Q fragments for the two K=32 chunks of HS=64 (kept in regs all loop)
    bf16x8 qf0 = *(const bf16x8*)(qvb + (size_t)(q0 + col) * HS + quad * 8);
    bf16x8 qf1 = *(const bf16x8*)(qvb + (size_t)(q0 + col) * HS + 32 + quad * 8);

    float m[4], l[4];
    f32x4 o[4];
#pragma unroll
    for (int r = 0; r < 4; ++r) { m[r] = -__builtin_inff(); l[r] = 0.f; }
#pragma unroll
    for (int h = 0; h < 4; ++h) o[h] = {0.f, 0.f, 0.f, 0.f};

    const float sc = 0.125f * 1.44269504088896f;  // scale * log2(e), use exp2
    const int nkt = (q0 + 15) / 32 + 1;           // causal K-tile count

    for (int kt = 0; kt < nkt; ++kt) {
        const int s0 = kt * 32;

        // ---- S = Q K^T (two 16-wide n-tiles) ----
        float sv[2][4];
#pragma unroll
        for (int nt = 0; nt < 2; ++nt) {
            const bf16* krow = kb + (size_t)(s0 + nt * 16 + col) * HS;
            bf16x8 b0 = *(const bf16x8*)(krow + quad * 8);
            bf16x8 b1 = *(const bf16x8*)(krow + 32 + quad * 8);
            f32x4 a4 = {0.f, 0.f, 0.f, 0.f};
            a4 = __builtin_amdgcn_mfma_f32_16x16x32_bf16(qf0, b0, a4, 0, 0, 0);
            a4 = __builtin_amdgcn_mfma_f32_16x16x32_bf16(qf1, b1, a4, 0, 0, 0);
#pragma unroll
            for (int r = 0; r < 4; ++r) sv[nt][r] = a4[r] * sc;
        }

        // causal mask: with q0 % 16 == 0 and 32-wide tiles, only last tile.
        // Every row keeps >=1 unmasked entry (s0 <= q0 <= q), so rm is finite.
        if (kt == nkt - 1) {
#pragma unroll
            for (int nt = 0; nt < 2; ++nt)
#pragma unroll
                for (int r = 0; r < 4; ++r)
                    if (s0 + nt * 16 + col > q0 + quad * 4 + r)
                        sv[nt][r] = -__builtin_inff();
        }

        // ---- online softmax: row reductions across the 16 lanes of a quad ----
        float mnew[4], alpha[4];
#pragma unroll
        for (int r = 0; r < 4; ++r) {
            float rm = fmaxf(sv[0][r], sv[1][r]);
#pragma unroll
            for (int off = 1; off < 16; off <<= 1)
                rm = fmaxf(rm, __shfl_xor(rm, off, 64));
            mnew[r] = fmaxf(m[r], rm);
            alpha[r] = exp2f(m[r] - mnew[r]);   // first iter: exp2(-inf)=0
            m[r] = mnew[r];
        }
        float p[2][4];
#pragma unroll
        for (int r = 0; r < 4; ++r) {
            p[0][r] = exp2f(sv[0][r] - mnew[r]);
            p[1][r] = exp2f(sv[1][r] - mnew[r]);
            float ps = p[0][r] + p[1][r];
#pragma unroll
            for (int off = 1; off < 16; off <<= 1)
                ps += __shfl_xor(ps, off, 64);
            l[r] = l[r] * alpha[r] + ps;
        }

        // ---- P: C-layout -> LDS -> A-layout (per-wave; DS ops are in-order) ----
#pragma unroll
        for (int nt = 0; nt < 2; ++nt)
#pragma unroll
            for (int r = 0; r < 4; ++r)
                plds[wave][quad * 4 + r][nt * 16 + col] = (bf16)p[nt][r];
        bf16x8 pa = *(const bf16x8*)&plds[wave][col][quad * 8];

        // ---- O = O*alpha + P V ----
#pragma unroll
        for (int h = 0; h < 4; ++h) {
            f32x4 oo = o[h];
            oo[0] *= alpha[0]; oo[1] *= alpha[1];
            oo[2] *= alpha[2]; oo[3] *= alpha[3];
            bf16x8 vb = *(const bf16x8*)(vTb + (size_t)(h * 16 + col) * T_SEQ + s0 + quad * 8);
            o[h] = __builtin_amdgcn_mfma_f32_16x16x32_bf16(pa, vb, oo, 0, 0, 0);
        }
    }

    // ---- epilogue: out = O / l (fp32 store) ----
#pragma unroll
    for (int h = 0; h < 4; ++h)
#pragma unroll
        for (int r = 0; r < 4; ++r) {
            size_t idx = ((size_t)b * T_SEQ + q0 + quad * 4 + r) * HS + h * 16 + col;
            out[idx] = o[h][r] / l[r];
        }
}

extern "C" void kernel_launch(void* const* d_in, const int* in_sizes, int n_in,
                              void* d_out, int out_size, void* d_ws, size_t ws_size,
                              hipStream_t stream) {
    const float* x  = (const float*)d_in[0];
    const float* Wk = (const float*)d_in[1];
    const float* Wv = (const float*)d_in[2];
    float* out = (float*)d_out;

    bf16* ws    = (bf16*)d_ws;
    bf16* wbf   = ws;                                    // 128*1024     = 256 KB
    bf16* kmat  = ws + (size_t)128 * 1024;               // 16384*64     = 2 MB
    bf16* qvmat = kmat + (size_t)16384 * 64;             // 2 MB
    bf16* qvT   = qvmat + (size_t)16384 * 64;            // 2 MB

    wcast_kernel<<<64, 256, 0, stream>>>(Wk, Wv, wbf);
    proj_kernel<<<256, 256, 0, stream>>>(x, wbf, kmat, qvmat, qvT);
    attn_kernel<<<256, 256, 0, stream>>>(kmat, qvmat, qvT, out);
}

// Round 3
// 242.165 us; speedup vs baseline: 1.1316x; 1.1316x over previous
//
#include <hip/hip_runtime.h>
#include <hip/hip_bf16.h>

typedef __bf16 bf16;
typedef __attribute__((ext_vector_type(8))) __bf16 bf16x8;
typedef __attribute__((ext_vector_type(4))) float f32x4;

#define T_SEQ 4096
#define D_EMB 1024
#define HS 64

// ---------------------------------------------------------------------------
// Kernel 0: cast Wk|Wv (fp32, 64x1024 each) -> bf16 workspace copies.
// ---------------------------------------------------------------------------
__global__ __launch_bounds__(256) void wcast_kernel(
    const float* __restrict__ Wk, const float* __restrict__ Wv,
    bf16* __restrict__ wbf)   // [128][1024]
{
    const int t = blockIdx.x * 256 + threadIdx.x;
    const int base = t * 8;
    const float* src = (base < 65536) ? (Wk + base) : (Wv + base - 65536);
    float4 f0 = *(const float4*)(src);
    float4 f1 = *(const float4*)(src + 4);
    bf16x8 o = {(__bf16)f0.x, (__bf16)f0.y, (__bf16)f0.z, (__bf16)f0.w,
                (__bf16)f1.x, (__bf16)f1.y, (__bf16)f1.z, (__bf16)f1.w};
    *(bf16x8*)(wbf + base) = o;
}

// ---------------------------------------------------------------------------
// Kernel 1: projection GEMM, K-split x4 for occupancy.
// Grid 1024: block = 16 rows x 128 cols; wave w covers K in [256w, 256w+256).
// Partials reduced through a flat f32 LDS buffer (b128-clean layout).
// ---------------------------------------------------------------------------
__global__ __launch_bounds__(256) void proj_kernel(
    const float* __restrict__ x,    // [16384][1024] fp32
    const bf16* __restrict__ wbf,   // [128][1024] bf16 (Wk rows 0-63, Wv 64-127)
    bf16* __restrict__ kmat,        // [16384][64]
    bf16* __restrict__ qvmat,       // [16384][64]
    bf16* __restrict__ qvT)         // [4][64][4096]
{
    __shared__ float red[4][2048];   // 32 KB: [wave][nt*256 + lane*4 + r]

    const int lane = threadIdx.x & 63;
    const int wave = threadIdx.x >> 6;
    const int col  = lane & 15;
    const int quad = lane >> 4;
    const int rowbase = blockIdx.x * 16;

    const float* xrow = x + (size_t)(rowbase + col) * D_EMB + wave * 256;

    f32x4 acc[8];
#pragma unroll
    for (int i = 0; i < 8; ++i) acc[i] = {0.f, 0.f, 0.f, 0.f};

    for (int k0 = 0; k0 < 256; k0 += 32) {
        float4 a0 = *(const float4*)(xrow + k0 + quad * 8);
        float4 a1 = *(const float4*)(xrow + k0 + quad * 8 + 4);
        bf16x8 a = {(__bf16)a0.x, (__bf16)a0.y, (__bf16)a0.z, (__bf16)a0.w,
                    (__bf16)a1.x, (__bf16)a1.y, (__bf16)a1.z, (__bf16)a1.w};
#pragma unroll
        for (int nt = 0; nt < 8; ++nt) {
            const bf16* wrow = wbf + (size_t)(nt * 16 + col) * D_EMB + wave * 256;
            bf16x8 b = *(const bf16x8*)(wrow + k0 + quad * 8);
            acc[nt] = __builtin_amdgcn_mfma_f32_16x16x32_bf16(a, b, acc[nt], 0, 0, 0);
        }
    }

    // write partials: flat idx = nt*256 + lane*4 + r  (b128, conflict-free)
#pragma unroll
    for (int nt = 0; nt < 8; ++nt)
        *(f32x4*)&red[wave][nt * 256 + lane * 4] = acc[nt];
    __syncthreads();

    // thread t reduces flat [8t, 8t+8) over the 4 waves
    const int t = threadIdx.x;
    f32x4 s0 = {0.f,0.f,0.f,0.f}, s1 = {0.f,0.f,0.f,0.f};
#pragma unroll
    for (int w = 0; w < 4; ++w) {
        s0 += *(const f32x4*)&red[w][t * 8];
        s1 += *(const f32x4*)&red[w][t * 8 + 4];
    }
    const int nt = t >> 5;
    const int L0 = (t & 31) * 2;
#pragma unroll
    for (int j2 = 0; j2 < 2; ++j2) {
        const int L  = L0 + j2;
        const int q  = L >> 4;
        const int cc = L & 15;
        const int c  = (nt & 3) * 16 + cc;
        f32x4 v = j2 ? s1 : s0;
#pragma unroll
        for (int r = 0; r < 4; ++r) {
            const int grow = rowbase + q * 4 + r;
            bf16 bv = (bf16)v[r];
            if (nt < 4) {
                kmat[(size_t)grow * HS + c] = bv;
            } else {
                qvmat[(size_t)grow * HS + c] = bv;
                const int bb = grow >> 12;
                const int tt = grow & (T_SEQ - 1);
                qvT[((size_t)bb * HS + c) * T_SEQ + tt] = bv;
            }
        }
    }
}

// ---------------------------------------------------------------------------
// Kernel 2: causal attention, fixed-offset softmax (no running max), q = v.
// Block = (batch, 16-row q-group); 4 waves split key tiles round-robin
// (t = wave, wave+4, ...). p = exp2(score*scale*log2e - 24): the 2^-24
// cancels exactly in O/l, so cross-wave combine is a pure sum via LDS.
// Diagonal score >= 0 guarantees l >= 2^-24 (no divide-by-zero).
// ---------------------------------------------------------------------------
__global__ __launch_bounds__(256) void attn_kernel(
    const bf16* __restrict__ kmat,   // [B*T][64]
    const bf16* __restrict__ qvmat,  // [B*T][64]
    const bf16* __restrict__ qvT,    // [B][64][T]
    float* __restrict__ out)         // [B*T][64] fp32
{
    __shared__ bf16 plds[4][16][40];              // P roundtrip, 5 KB
    __shared__ __align__(16) float obuf[4][16][68];  // O partials, 17.4 KB (pad 68)
    __shared__ float lbuf[4][16];                 // l partials

    const int lane = threadIdx.x & 63;
    const int wave = threadIdx.x >> 6;
    const int col  = lane & 15;
    const int quad = lane >> 4;

    const int b  = blockIdx.x >> 8;
    const int g  = blockIdx.x & 255;
    const int q0 = g * 16;

    const bf16* qvb = qvmat + (size_t)b * T_SEQ * HS;
    const bf16* kb  = kmat  + (size_t)b * T_SEQ * HS;
    const bf16* vTb = qvT   + (size_t)b * HS * T_SEQ;

    bf16x8 qf0 = *(const bf16x8*)(qvb + (size_t)(q0 + col) * HS + quad * 8);
    bf16x8 qf1 = *(const bf16x8*)(qvb + (size_t)(q0 + col) * HS + 32 + quad * 8);

    f32x4 o[4];
    float lp[4];
#pragma unroll
    for (int h = 0; h < 4; ++h) o[h] = {0.f, 0.f, 0.f, 0.f};
#pragma unroll
    for (int r = 0; r < 4; ++r) lp[r] = 0.f;

    const float sc = 0.125f * 1.44269504088896f;
    const int nk = (q0 + 16 + 31) >> 5;          // causal tile count

    for (int t = wave; t < nk; t += 4) {
        const int s0 = t * 32;

        // ---- S = Q K^T, p = exp2(S*sc - 24) ----
        float p[2][4];
#pragma unroll
        for (int nt = 0; nt < 2; ++nt) {
            const bf16* krow = kb + (size_t)(s0 + nt * 16 + col) * HS;
            bf16x8 b0 = *(const bf16x8*)(krow + quad * 8);
            bf16x8 b1 = *(const bf16x8*)(krow + 32 + quad * 8);
            f32x4 a4 = {0.f, 0.f, 0.f, 0.f};
            a4 = __builtin_amdgcn_mfma_f32_16x16x32_bf16(qf0, b0, a4, 0, 0, 0);
            a4 = __builtin_amdgcn_mfma_f32_16x16x32_bf16(qf1, b1, a4, 0, 0, 0);
#pragma unroll
            for (int r = 0; r < 4; ++r)
                p[nt][r] = exp2f(fmaf(a4[r], sc, -24.f));
        }

        // causal mask on the last tile: zero the masked probabilities
        if (t == nk - 1) {
#pragma unroll
            for (int nt = 0; nt < 2; ++nt)
#pragma unroll
                for (int r = 0; r < 4; ++r)
                    if (s0 + nt * 16 + col > q0 + quad * 4 + r)
                        p[nt][r] = 0.f;
        }

#pragma unroll
        for (int r = 0; r < 4; ++r) lp[r] += p[0][r] + p[1][r];

        // ---- P: C-layout -> LDS -> A-layout (wave-private, in-order DS) ----
#pragma unroll
        for (int nt = 0; nt < 2; ++nt)
#pragma unroll
            for (int r = 0; r < 4; ++r)
                plds[wave][quad * 4 + r][nt * 16 + col] = (bf16)p[nt][r];
        bf16x8 pa = *(const bf16x8*)&plds[wave][col][quad * 8];

        // ---- O += P V ----
#pragma unroll
        for (int h = 0; h < 4; ++h) {
            bf16x8 vb = *(const bf16x8*)(vTb + (size_t)(h * 16 + col) * T_SEQ + s0 + quad * 8);
            o[h] = __builtin_amdgcn_mfma_f32_16x16x32_bf16(pa, vb, o[h], 0, 0, 0);
        }
    }

    // ---- per-wave row-sum of l (16-lane butterfly), write partials ----
#pragma unroll
    for (int r = 0; r < 4; ++r) {
        float lr = lp[r];
#pragma unroll
        for (int off = 1; off < 16; off <<= 1)
            lr += __shfl_xor(lr, off, 64);
        if (col == 0) lbuf[wave][quad * 4 + r] = lr;
    }
#pragma unroll
    for (int h = 0; h < 4; ++h)
#pragma unroll
        for (int r = 0; r < 4; ++r)
            obuf[wave][quad * 4 + r][h * 16 + col] = o[h][r];
    __syncthreads();

    // ---- combine: out = (sum_w O_w) / (sum_w l_w) ----
    const int tid = threadIdx.x;
    const int row = tid >> 4;
    const int c4  = (tid & 15) * 4;
    f32x4 os = {0.f, 0.f, 0.f, 0.f};
    float ls = 0.f;
#pragma unroll
    for (int w = 0; w < 4; ++w) {
        os += *(const f32x4*)&obuf[w][row][c4];
        ls += lbuf[w][row];
    }
    float inv = 1.f / ls;
    float* op = out + ((size_t)b * T_SEQ + q0 + row) * HS + c4;
    op[0] = os[0] * inv; op[1] = os[1] * inv;
    op[2] = os[2] * inv; op[3] = os[3] * inv;
}

extern "C" void kernel_launch(void* const* d_in, const int* in_sizes, int n_in,
                              void* d_out, int out_size, void* d_ws, size_t ws_size,
                              hipStream_t stream) {
    const float* x  = (const float*)d_in[0];
    const float* Wk = (const float*)d_in[1];
    const float* Wv = (const float*)d_in[2];
    float* out = (float*)d_out;

    bf16* ws    = (bf16*)d_ws;
    bf16* wbf   = ws;                                    // 256 KB
    bf16* kmat  = ws + (size_t)128 * 1024;               // 2 MB
    bf16* qvmat = kmat + (size_t)16384 * 64;             // 2 MB
    bf16* qvT   = qvmat + (size_t)16384 * 64;            // 2 MB

    wcast_kernel<<<64, 256, 0, stream>>>(Wk, Wv, wbf);
    proj_kernel<<<1024, 256, 0, stream>>>(x, wbf, kmat, qvmat, qvT);
    attn_kernel<<<1024, 256, 0, stream>>>(kmat, qvmat, qvT, out);
}

// Round 4
// 191.425 us; speedup vs baseline: 1.4315x; 1.2651x over previous
//
#include <hip/hip_runtime.h>
#include <hip/hip_bf16.h>

typedef __bf16 bf16;
typedef __attribute__((ext_vector_type(8))) __bf16 bf16x8;
typedef __attribute__((ext_vector_type(4))) float f32x4;

#define T_SEQ 4096
#define D_EMB 1024
#define HS 64

__device__ __forceinline__ float fexp2(float x) {
#if __has_builtin(__builtin_amdgcn_exp2f)
    return __builtin_amdgcn_exp2f(x);   // raw v_exp_f32
#else
    return exp2f(x);
#endif
}

// ---------------------------------------------------------------------------
// Kernel 0: cast Wk|Wv (fp32, 64x1024 each) -> bf16 workspace copies.
// ---------------------------------------------------------------------------
__global__ __launch_bounds__(256) void wcast_kernel(
    const float* __restrict__ Wk, const float* __restrict__ Wv,
    bf16* __restrict__ wbf)   // [128][1024]
{
    const int t = blockIdx.x * 256 + threadIdx.x;
    const int base = t * 8;
    const float* src = (base < 65536) ? (Wk + base) : (Wv + base - 65536);
    float4 f0 = *(const float4*)(src);
    float4 f1 = *(const float4*)(src + 4);
    bf16x8 o = {(__bf16)f0.x, (__bf16)f0.y, (__bf16)f0.z, (__bf16)f0.w,
                (__bf16)f1.x, (__bf16)f1.y, (__bf16)f1.z, (__bf16)f1.w};
    *(bf16x8*)(wbf + base) = o;
}

// ---------------------------------------------------------------------------
// Kernel 1: projection GEMM, K-split x4 (unchanged from round 3).
// ---------------------------------------------------------------------------
__global__ __launch_bounds__(256) void proj_kernel(
    const float* __restrict__ x,    // [16384][1024] fp32
    const bf16* __restrict__ wbf,   // [128][1024] bf16 (Wk rows 0-63, Wv 64-127)
    bf16* __restrict__ kmat,        // [16384][64]
    bf16* __restrict__ qvmat,       // [16384][64]
    bf16* __restrict__ qvT)         // [4][64][4096]
{
    __shared__ float red[4][2048];   // 32 KB

    const int lane = threadIdx.x & 63;
    const int wave = threadIdx.x >> 6;
    const int col  = lane & 15;
    const int quad = lane >> 4;
    const int rowbase = blockIdx.x * 16;

    const float* xrow = x + (size_t)(rowbase + col) * D_EMB + wave * 256;

    f32x4 acc[8];
#pragma unroll
    for (int i = 0; i < 8; ++i) acc[i] = {0.f, 0.f, 0.f, 0.f};

    for (int k0 = 0; k0 < 256; k0 += 32) {
        float4 a0 = *(const float4*)(xrow + k0 + quad * 8);
        float4 a1 = *(const float4*)(xrow + k0 + quad * 8 + 4);
        bf16x8 a = {(__bf16)a0.x, (__bf16)a0.y, (__bf16)a0.z, (__bf16)a0.w,
                    (__bf16)a1.x, (__bf16)a1.y, (__bf16)a1.z, (__bf16)a1.w};
#pragma unroll
        for (int nt = 0; nt < 8; ++nt) {
            const bf16* wrow = wbf + (size_t)(nt * 16 + col) * D_EMB + wave * 256;
            bf16x8 b = *(const bf16x8*)(wrow + k0 + quad * 8);
            acc[nt] = __builtin_amdgcn_mfma_f32_16x16x32_bf16(a, b, acc[nt], 0, 0, 0);
        }
    }

#pragma unroll
    for (int nt = 0; nt < 8; ++nt)
        *(f32x4*)&red[wave][nt * 256 + lane * 4] = acc[nt];
    __syncthreads();

    const int t = threadIdx.x;
    f32x4 s0 = {0.f,0.f,0.f,0.f}, s1 = {0.f,0.f,0.f,0.f};
#pragma unroll
    for (int w = 0; w < 4; ++w) {
        s0 += *(const f32x4*)&red[w][t * 8];
        s1 += *(const f32x4*)&red[w][t * 8 + 4];
    }
    const int nt = t >> 5;
    const int L0 = (t & 31) * 2;
#pragma unroll
    for (int j2 = 0; j2 < 2; ++j2) {
        const int L  = L0 + j2;
        const int q  = L >> 4;
        const int cc = L & 15;
        const int c  = (nt & 3) * 16 + cc;
        f32x4 v = j2 ? s1 : s0;
#pragma unroll
        for (int r = 0; r < 4; ++r) {
            const int grow = rowbase + q * 4 + r;
            bf16 bv = (bf16)v[r];
            if (nt < 4) {
                kmat[(size_t)grow * HS + c] = bv;
            } else {
                qvmat[(size_t)grow * HS + c] = bv;
                const int bb = grow >> 12;
                const int tt = grow & (T_SEQ - 1);
                qvT[((size_t)bb * HS + c) * T_SEQ + tt] = bv;
            }
        }
    }
}

// ---------------------------------------------------------------------------
// Kernel 2: causal attention, fixed-offset softmax, q = v.
// 512 blocks; block handles q-group pair (g, 255-g) of one batch -> every
// block does ~130 key-tiles (balanced). 4 waves split a group's tiles
// round-robin. Explicit K/V register prefetch (tile t+4 issued before
// computing tile t) to hide L2 latency.
// ---------------------------------------------------------------------------
__global__ __launch_bounds__(256) void attn_kernel(
    const bf16* __restrict__ kmat,   // [B*T][64]
    const bf16* __restrict__ qvmat,  // [B*T][64]
    const bf16* __restrict__ qvT,    // [B][64][T]
    float* __restrict__ out)         // [B*T][64] fp32
{
    __shared__ bf16 plds[4][16][40];                 // P roundtrip, 5 KB
    __shared__ __align__(16) float obuf[4][16][68];  // O partials, 17.4 KB
    __shared__ float lbuf[4][16];

    const int lane = threadIdx.x & 63;
    const int wave = threadIdx.x >> 6;
    const int col  = lane & 15;
    const int quad = lane >> 4;

    const int b     = blockIdx.x >> 7;     // 0..3
    const int pairg = blockIdx.x & 127;    // 0..127

    const bf16* qvb = qvmat + (size_t)b * T_SEQ * HS;
    const bf16* kb  = kmat  + (size_t)b * T_SEQ * HS;
    const bf16* vTb = qvT   + (size_t)b * HS * T_SEQ;

    const float sc = 0.125f * 1.44269504088896f;

#pragma unroll 1
    for (int half = 0; half < 2; ++half) {
        const int g  = half ? (255 - pairg) : pairg;
        const int q0 = g * 16;

        bf16x8 qf0 = *(const bf16x8*)(qvb + (size_t)(q0 + col) * HS + quad * 8);
        bf16x8 qf1 = *(const bf16x8*)(qvb + (size_t)(q0 + col) * HS + 32 + quad * 8);

        f32x4 o[4];
        float lp[4];
#pragma unroll
        for (int h = 0; h < 4; ++h) o[h] = {0.f, 0.f, 0.f, 0.f};
#pragma unroll
        for (int r = 0; r < 4; ++r) lp[r] = 0.f;

        const int nk = (q0 + 16 + 31) >> 5;   // causal tile count

        bf16x8 kc[4], vc[4];
        int t = wave;
        if (t < nk) {
            const int s0 = t * 32;
            const bf16* kr0 = kb + (size_t)(s0 + col) * HS;
            const bf16* kr1 = kb + (size_t)(s0 + 16 + col) * HS;
            kc[0] = *(const bf16x8*)(kr0 + quad * 8);
            kc[1] = *(const bf16x8*)(kr0 + 32 + quad * 8);
            kc[2] = *(const bf16x8*)(kr1 + quad * 8);
            kc[3] = *(const bf16x8*)(kr1 + 32 + quad * 8);
#pragma unroll
            for (int h = 0; h < 4; ++h)
                vc[h] = *(const bf16x8*)(vTb + (size_t)(h * 16 + col) * T_SEQ + s0 + quad * 8);
        }

        while (t < nk) {
            const int tn = t + 4;
            const int tl = (tn < nk) ? tn : t;   // clamp: harmless reload on last iter
            // ---- prefetch tile tl ----
            bf16x8 kn[4], vn[4];
            {
                const int s0n = tl * 32;
                const bf16* kr0 = kb + (size_t)(s0n + col) * HS;
                const bf16* kr1 = kb + (size_t)(s0n + 16 + col) * HS;
                kn[0] = *(const bf16x8*)(kr0 + quad * 8);
                kn[1] = *(const bf16x8*)(kr0 + 32 + quad * 8);
                kn[2] = *(const bf16x8*)(kr1 + quad * 8);
                kn[3] = *(const bf16x8*)(kr1 + 32 + quad * 8);
#pragma unroll
                for (int h = 0; h < 4; ++h)
                    vn[h] = *(const bf16x8*)(vTb + (size_t)(h * 16 + col) * T_SEQ + s0n + quad * 8);
            }

            // ---- compute tile t with kc/vc ----
            const int s0 = t * 32;
            float p[2][4];
#pragma unroll
            for (int ntile = 0; ntile < 2; ++ntile) {
                f32x4 a4 = {0.f, 0.f, 0.f, 0.f};
                a4 = __builtin_amdgcn_mfma_f32_16x16x32_bf16(qf0, kc[ntile * 2], a4, 0, 0, 0);
                a4 = __builtin_amdgcn_mfma_f32_16x16x32_bf16(qf1, kc[ntile * 2 + 1], a4, 0, 0, 0);
#pragma unroll
                for (int r = 0; r < 4; ++r)
                    p[ntile][r] = fexp2(fmaf(a4[r], sc, -24.f));
            }

            if (t == nk - 1) {   // causal mask: zero masked probabilities
#pragma unroll
                for (int ntile = 0; ntile < 2; ++ntile)
#pragma unroll
                    for (int r = 0; r < 4; ++r)
                        if (s0 + ntile * 16 + col > q0 + quad * 4 + r)
                            p[ntile][r] = 0.f;
            }

#pragma unroll
            for (int r = 0; r < 4; ++r) lp[r] += p[0][r] + p[1][r];

            // ---- P: C-layout -> LDS -> A-layout (wave-private, in-order DS) ----
#pragma unroll
            for (int ntile = 0; ntile < 2; ++ntile)
#pragma unroll
                for (int r = 0; r < 4; ++r)
                    plds[wave][quad * 4 + r][ntile * 16 + col] = (bf16)p[ntile][r];
            bf16x8 pa = *(const bf16x8*)&plds[wave][col][quad * 8];

            // ---- O += P V ----
#pragma unroll
            for (int h = 0; h < 4; ++h)
                o[h] = __builtin_amdgcn_mfma_f32_16x16x32_bf16(pa, vc[h], o[h], 0, 0, 0);

            // rotate prefetch
#pragma unroll
            for (int i = 0; i < 4; ++i) { kc[i] = kn[i]; vc[i] = vn[i]; }
            t = tn;
        }

        // ---- per-wave row-sum of l, write partials ----
#pragma unroll
        for (int r = 0; r < 4; ++r) {
            float lr = lp[r];
#pragma unroll
            for (int off = 1; off < 16; off <<= 1)
                lr += __shfl_xor(lr, off, 64);
            if (col == 0) lbuf[wave][quad * 4 + r] = lr;
        }
#pragma unroll
        for (int h = 0; h < 4; ++h)
#pragma unroll
            for (int r = 0; r < 4; ++r)
                obuf[wave][quad * 4 + r][h * 16 + col] = o[h][r];
        __syncthreads();

        // ---- combine: out = (sum_w O_w) / (sum_w l_w) ----
        const int tid = threadIdx.x;
        const int row = tid >> 4;
        const int c4  = (tid & 15) * 4;
        f32x4 os = {0.f, 0.f, 0.f, 0.f};
        float ls = 0.f;
#pragma unroll
        for (int w = 0; w < 4; ++w) {
            os += *(const f32x4*)&obuf[w][row][c4];
            ls += lbuf[w][row];
        }
        float inv = 1.f / ls;
        float* op = out + ((size_t)b * T_SEQ + q0 + row) * HS + c4;
        op[0] = os[0] * inv; op[1] = os[1] * inv;
        op[2] = os[2] * inv; op[3] = os[3] * inv;

        __syncthreads();   // obuf/lbuf reused by second group
    }
}

extern "C" void kernel_launch(void* const* d_in, const int* in_sizes, int n_in,
                              void* d_out, int out_size, void* d_ws, size_t ws_size,
                              hipStream_t stream) {
    const float* x  = (const float*)d_in[0];
    const float* Wk = (const float*)d_in[1];
    const float* Wv = (const float*)d_in[2];
    float* out = (float*)d_out;

    bf16* ws    = (bf16*)d_ws;
    bf16* wbf   = ws;                                    // 256 KB
    bf16* kmat  = ws + (size_t)128 * 1024;               // 2 MB
    bf16* qvmat = kmat + (size_t)16384 * 64;             // 2 MB
    bf16* qvT   = qvmat + (size_t)16384 * 64;            // 2 MB

    wcast_kernel<<<64, 256, 0, stream>>>(Wk, Wv, wbf);
    proj_kernel<<<1024, 256, 0, stream>>>(x, wbf, kmat, qvmat, qvT);
    attn_kernel<<<512, 256, 0, stream>>>(kmat, qvmat, qvT, out);
}